// Round 2
// baseline (659.535 us; speedup 1.0000x reference)
//
#include <hip/hip_runtime.h>
#include <hip/hip_bf16.h>

// RWKV7 WKV chunked scan. T=4096, H=32, N=64. Output fp32 (y then S_final).
//
// Pass 1 (R5): TWO waves per (chunk, head). Fused P/M scan, column-split:
//   wave wv owns state columns [wv*32, wv*32+32) of BOTH SP and SM. Partial
//   sa/y/q exchanged through double-buffered LDS, ONE barrier per step.
//   readlane broadcasts with inline-constant lane index 0..31.
// Pass 2 (R6): zero-LDS, zero-barrier. Block = (head h, row-group g): 8 waves,
//   wave = row r = g*8+wv, lane = column j. S[r][j] lives in the lane; the
//   k-dot broadcasts S[r][k] via readlane (the wave IS the row). M's column j
//   (Mt[j*64+k], 128B contiguous per lane) is loaded global->reg with a raw
//   uint4 double-buffer: issue next chunk's loads BEFORE the k-loop, convert
//   AFTER it, so HBM/L2 latency hides under compute. Block id = g*32+h puts
//   all 8 row-groups of a head on ONE XCD (bid%8 = h%8) so Mt is L2-shared
//   instead of fetched 8x from HBM.
// Pass 3 (R6): zero-LDS. lane = output row i, Srow in 64 VGPRs (uint4 loads);
//   each wave's 16 rho rows are loaded lane-distributed (1 coalesced load per
//   row) and broadcast via readlane. Replaces 1024 scalar ds_read_b32 +
//   64 scalar global loads per thread of the old version.

#define Tt 4096
#define Hh 32
#define Nn 64
#define Ll 64              // chunk length
#define Cc 64              // number of chunks
#define HN (Hh * Nn)       // 2048
#define NN (Nn * Nn)       // 4096

__device__ __forceinline__ float ldf(const float* p) { return *p; }
__device__ __forceinline__ float ldf(const __hip_bfloat16* p) { return __bfloat162float(*p); }
__device__ __forceinline__ void stf(float* p, float v) { *p = v; }
__device__ __forceinline__ void stf(__hip_bfloat16* p, float v) { *p = __float2bfloat16(v); }

__device__ __forceinline__ float rl(float v, int j) {
    return __int_as_float(__builtin_amdgcn_readlane(__float_as_int(v), j));
}

// load 64 consecutive elements (fp32 or bf16) into 64 fp32 registers, vectorized
__device__ __forceinline__ void ld64v(const float* p, float (&d)[Nn]) {
    const float4* q = (const float4*)p;
    #pragma unroll
    for (int i = 0; i < 16; ++i) {
        float4 v = q[i];
        d[4*i+0] = v.x; d[4*i+1] = v.y; d[4*i+2] = v.z; d[4*i+3] = v.w;
    }
}
__device__ __forceinline__ void ld64v(const __hip_bfloat16* p, float (&d)[Nn]) {
    const uint4* q = (const uint4*)p;
    #pragma unroll
    for (int i = 0; i < 8; ++i) {
        uint4 v = q[i];
        d[8*i+0] = __uint_as_float(v.x << 16); d[8*i+1] = __uint_as_float(v.x & 0xffff0000u);
        d[8*i+2] = __uint_as_float(v.y << 16); d[8*i+3] = __uint_as_float(v.y & 0xffff0000u);
        d[8*i+4] = __uint_as_float(v.z << 16); d[8*i+5] = __uint_as_float(v.z & 0xffff0000u);
        d[8*i+6] = __uint_as_float(v.w << 16); d[8*i+7] = __uint_as_float(v.w & 0xffff0000u);
    }
}

// ---------------------------------------------------------------- pass 1
template <typename ST>
__global__ __launch_bounds__(128, 4)
void pass1_scan(const float* __restrict__ rr, const float* __restrict__ ww,
                const float* __restrict__ kk, const float* __restrict__ vv,
                const float* __restrict__ aa, const float* __restrict__ bb,
                float* __restrict__ ylocal,
                ST* __restrict__ rho, ST* __restrict__ Mt, ST* __restrict__ Pt)
{
    const int c    = blockIdx.x >> 5;      // chunk
    const int h    = blockIdx.x & 31;      // head
    const int tid  = threadIdx.x;
    const int lane = tid & 63;             // row i
    const int wv   = tid >> 6;             // column-half 0/1
    const int j0   = __builtin_amdgcn_readfirstlane(wv << 5);

    // partial-exchange buffers, double-buffered over step parity
    __shared__ float2 ex1[2][2][64];       // [par][wave][row] = {saP, saM} partials
    __shared__ float  ex2[2][2][64];       // [par][wave][row] = partial the OTHER wave finalizes

    float SP[32];                          // P scan, local columns
    float SM[32];                          // M scan, local columns
    #pragma unroll
    for (int jj = 0; jj < 32; ++jj) {
        SP[jj] = 0.0f;
        SM[jj] = (j0 + jj == lane) ? 1.0f : 0.0f;
    }

    int base = (c * Ll * Hh + h) * Nn;     // element offset of step t
    const int lv = j0 + (lane & 31);       // broadcast-source element this lane carries
    float ca = aa[base + lv];
    float cw = ww[base + lv];
    float cb = bb[base + lv];
    float cr = rr[base + lv];
    float ck = kk[base + lv];
    float cv = vv[base + lane];            // per-row value (full vector per lane)

    float py = 0.f, pq = 0.f;              // y/q partials of step t-1 (exchanged next iter)

    for (int t = 0; t < Ll; ++t) {
        // partial sa over local columns (shared a broadcasts between both scans)
        float p0 = 0.f, p1 = 0.f, m0 = 0.f, m1 = 0.f;
        #pragma unroll
        for (int jj = 0; jj < 32; jj += 2) {
            const float a0 = rl(ca, jj), a1 = rl(ca, jj + 1);
            p0 += SP[jj + 0] * a0;  m0 += SM[jj + 0] * a0;
            p1 += SP[jj + 1] * a1;  m1 += SM[jj + 1] * a1;
        }
        const float pP = p0 + p1, pM = m0 + m1;

        ex1[t & 1][wv][lane] = make_float2(pP, pM);
        if (t > 0) ex2[(t - 1) & 1][wv][lane] = (wv == 0) ? pq : py;
        __syncthreads();
        const float2 o = ex1[t & 1][wv ^ 1][lane];
        const float saP = pP + o.x;
        const float saM = pM + o.y;
        if (t > 0) {                        // finish + store step t-1 outputs
            const int ob = base - HN + lane;
            if (wv == 0) ylocal[ob] = py + ex2[(t - 1) & 1][1][lane];
            else         stf(&rho[ob], pq + ex2[(t - 1) & 1][0][lane]);
        }

        // prefetch next step's vectors (uniform branch; hides under update loop)
        float na = 0.f, nw = 0.f, nb = 0.f, nr = 0.f, nk = 0.f, nv = 0.f;
        if (t + 1 < Ll) {
            const int b2 = base + HN;
            na = aa[b2 + lv]; nw = ww[b2 + lv]; nb = bb[b2 + lv];
            nr = rr[b2 + lv]; nk = kk[b2 + lv]; nv = vv[b2 + lane];
        }

        // S = S*w + sa*b (+ v*k); accumulate local y/q partials
        float y0 = 0.f, y1 = 0.f, q0 = 0.f, q1 = 0.f;
        #pragma unroll
        for (int jj = 0; jj < 32; jj += 2) {
            const float w0 = rl(cw, jj), w1 = rl(cw, jj + 1);
            const float b0 = rl(cb, jj), b1 = rl(cb, jj + 1);
            const float k0 = rl(ck, jj), k1 = rl(ck, jj + 1);
            const float r0 = rl(cr, jj), r1 = rl(cr, jj + 1);
            SP[jj + 0] = SP[jj + 0] * w0 + saP * b0 + cv * k0;
            SP[jj + 1] = SP[jj + 1] * w1 + saP * b1 + cv * k1;
            SM[jj + 0] = SM[jj + 0] * w0 + saM * b0;
            SM[jj + 1] = SM[jj + 1] * w1 + saM * b1;
            y0 += SP[jj + 0] * r0;
            y1 += SP[jj + 1] * r1;
            q0 += SM[jj + 0] * r0;
            q1 += SM[jj + 1] * r1;
        }
        py = y0 + y1;
        pq = q0 + q1;

        base += HN;
        ca = na; cw = nw; cb = nb; cr = nr; ck = nk; cv = nv;
    }

    // drain the deferred outputs of the final step
    {
        ex2[(Ll - 1) & 1][wv][lane] = (wv == 0) ? pq : py;
        __syncthreads();
        const int ob = base - HN + lane;
        if (wv == 0) ylocal[ob] = py + ex2[(Ll - 1) & 1][1][lane];
        else         stf(&rho[ob], pq + ex2[(Ll - 1) & 1][0][lane]);
    }

    // chunk-final matrices, stored transposed: [c][h][col j][row lane]
    const size_t mb = ((size_t)(c * Hh) + h) * NN;
    #pragma unroll
    for (int jj = 0; jj < 32; ++jj) {
        stf(&Pt[mb + (size_t)(j0 + jj) * Nn + lane], SP[jj]);
        stf(&Mt[mb + (size_t)(j0 + jj) * Nn + lane], SM[jj]);
    }
}

// ---------------------------------------------------------------- pass 2
// one chunk step: store S_before, prefetch next M column + P, k-dot, update s
template <typename ST>
__device__ __forceinline__ void kdot(float& s, const float (&m)[Nn], float pp) {
    float a0 = pp, a1 = 0.f, a2 = 0.f, a3 = 0.f;
    #pragma unroll
    for (int k = 0; k < Nn; k += 4) {
        a0 += rl(s, k + 0) * m[k + 0];
        a1 += rl(s, k + 1) * m[k + 1];
        a2 += rl(s, k + 2) * m[k + 2];
        a3 += rl(s, k + 3) * m[k + 3];
    }
    s = (a0 + a1) + (a2 + a3);
}

template <typename ST>
__device__ __forceinline__ void step_chunk(
    int c, int h, int r, int j, float& s,
    float (&mcur)[Nn], float (&mnxt)[Nn], float& ppc, float& ppn,
    const ST* __restrict__ Mt, const ST* __restrict__ Pt, ST* __restrict__ Sst)
{
    // S_before[c] out (row-major [r][j], coalesced)
    stf(&Sst[((size_t)(c * Hh) + h) * NN + (size_t)r * Nn + j], s);

    const bool pf = (c + 1 < Cc);
    const size_t nb = ((size_t)((c + 1) * Hh) + h) * NN;

    if constexpr (sizeof(ST) == 2) {
        uint4 raw[8];
        if (pf) {
            const uint4* q = (const uint4*)&Mt[nb + (size_t)j * Nn];
            #pragma unroll
            for (int i = 0; i < 8; ++i) raw[i] = q[i];       // issue loads early
            ppn = ldf(&Pt[nb + (size_t)j * Nn + r]);
        }
        kdot<ST>(s, mcur, ppc);                              // compute hides latency
        if (pf) {
            #pragma unroll
            for (int i = 0; i < 8; ++i) {                    // convert after compute
                mnxt[8*i+0] = __uint_as_float(raw[i].x << 16);
                mnxt[8*i+1] = __uint_as_float(raw[i].x & 0xffff0000u);
                mnxt[8*i+2] = __uint_as_float(raw[i].y << 16);
                mnxt[8*i+3] = __uint_as_float(raw[i].y & 0xffff0000u);
                mnxt[8*i+4] = __uint_as_float(raw[i].z << 16);
                mnxt[8*i+5] = __uint_as_float(raw[i].z & 0xffff0000u);
                mnxt[8*i+6] = __uint_as_float(raw[i].w << 16);
                mnxt[8*i+7] = __uint_as_float(raw[i].w & 0xffff0000u);
            }
        }
    } else {
        if (pf) {
            ld64v(&Mt[nb + (size_t)j * Nn], mnxt);
            ppn = ldf(&Pt[nb + (size_t)j * Nn + r]);
        }
        kdot<ST>(s, mcur, ppc);
    }
}

template <typename ST>
__global__ __launch_bounds__(512, 2)
void pass2_chain(const ST* __restrict__ Mt, const ST* __restrict__ Pt,
                 const float* __restrict__ st0, ST* __restrict__ Sst,
                 float* __restrict__ sfin)
{
    // bid = g*32 + h  ->  bid%8 = h%8: all 8 row-groups of head h on ONE XCD
    const int bid = blockIdx.x;
    const int h   = bid & 31;
    const int g   = bid >> 5;
    const int tid = threadIdx.x;
    const int j   = tid & 63;          // column (lane)
    const int wv  = tid >> 6;          // wave 0..7
    const int r   = g * 8 + wv;        // row

    float s = st0[(h * Nn + r) * Nn + j];

    float mA[Nn], mB[Nn];
    float ppA = 0.f, ppB = 0.f;
    ld64v(&Mt[(size_t)h * NN + (size_t)j * Nn], mA);            // chunk 0
    ppA = ldf(&Pt[(size_t)h * NN + (size_t)j * Nn + r]);

    for (int c = 0; c < Cc; c += 2) {
        step_chunk<ST>(c,     h, r, j, s, mA, mB, ppA, ppB, Mt, Pt, Sst);
        step_chunk<ST>(c + 1, h, r, j, s, mB, mA, ppB, ppA, Mt, Pt, Sst);
    }

    // final state -> d_out tail (fp32)
    sfin[(h * Nn + r) * Nn + j] = s;
}

// ---------------------------------------------------------------- pass 3
template <typename ST>
__global__ __launch_bounds__(256, 4)
void pass3_fix(const ST* __restrict__ rho, const ST* __restrict__ Sst,
               float* __restrict__ y)
{
    const int c    = blockIdx.x >> 5;   // chunk
    const int h    = blockIdx.x & 31;   // head
    const int tid  = threadIdx.x;
    const int lane = tid & 63;          // output row i
    const int tq   = tid >> 6;          // wave 0..3, handles t = tq*16 + m

    float Srow[Nn];  // S_before[c][h] row `lane`
    ld64v(&Sst[((size_t)(c * Hh) + h) * NN + (size_t)lane * Nn], Srow);

    // each wave's 16 rho rows, lane-distributed: rt[m] = rho[t][h][lane]
    float rt[16];
    #pragma unroll
    for (int m = 0; m < 16; ++m)
        rt[m] = ldf(&rho[((size_t)(c * Ll + tq * 16 + m) * Hh + h) * Nn + lane]);

    #pragma unroll
    for (int m = 0; m < 16; ++m) {
        float a0 = 0.f, a1 = 0.f, a2 = 0.f, a3 = 0.f;
        #pragma unroll
        for (int j = 0; j < Nn; j += 4) {
            a0 += rl(rt[m], j + 0) * Srow[j + 0];
            a1 += rl(rt[m], j + 1) * Srow[j + 1];
            a2 += rl(rt[m], j + 2) * Srow[j + 2];
            a3 += rl(rt[m], j + 3) * Srow[j + 3];
        }
        const size_t oy = ((size_t)(c * Ll + tq * 16 + m) * Hh + h) * Nn + lane;
        y[oy] = y[oy] + ((a0 + a1) + (a2 + a3));
    }
}

// ------------------------------------------- zero-scratch sequential fallback
__global__ __launch_bounds__(64, 1)
void seq_scan(const float* __restrict__ rr, const float* __restrict__ ww,
              const float* __restrict__ kk, const float* __restrict__ vv,
              const float* __restrict__ aa, const float* __restrict__ bb,
              const float* __restrict__ st0,
              float* __restrict__ y, float* __restrict__ sfin)
{
    const int h    = blockIdx.x;
    const int lane = threadIdx.x;          // row i

    float S[Nn];
    #pragma unroll
    for (int j = 0; j < Nn; ++j) S[j] = st0[(h * Nn + lane) * Nn + j];

    int base = h * Nn;
    float ca = aa[base + lane], cw = ww[base + lane], cb = bb[base + lane];
    float cr = rr[base + lane], ck = kk[base + lane], cv = vv[base + lane];

    for (int t = 0; t < Tt; ++t) {
        float na = 0.f, nw = 0.f, nb = 0.f, nr = 0.f, nk = 0.f, nv = 0.f;
        if (t + 1 < Tt) {
            const int b2 = base + HN + lane;
            na = aa[b2]; nw = ww[b2]; nb = bb[b2];
            nr = rr[b2]; nk = kk[b2]; nv = vv[b2];
        }

        float s0 = 0.f, s1 = 0.f;
        #pragma unroll
        for (int j = 0; j < Nn; j += 2) {
            s0 += S[j + 0] * rl(ca, j);
            s1 += S[j + 1] * rl(ca, j + 1);
        }
        const float sa = s0 + s1;

        float y0 = 0.f, y1 = 0.f;
        #pragma unroll
        for (int j = 0; j < Nn; j += 2) {
            const float w0 = rl(cw, j), w1 = rl(cw, j + 1);
            const float b0 = rl(cb, j), b1 = rl(cb, j + 1);
            const float k0 = rl(ck, j), k1 = rl(ck, j + 1);
            const float r0 = rl(cr, j), r1 = rl(cr, j + 1);
            S[j + 0] = S[j + 0] * w0 + sa * b0 + cv * k0;
            S[j + 1] = S[j + 1] * w1 + sa * b1 + cv * k1;
            y0 += S[j + 0] * r0;
            y1 += S[j + 1] * r1;
        }
        y[base + lane] = y0 + y1;
        base += HN;
        ca = na; cw = nw; cb = nb; cr = nr; ck = nk; cv = nv;
    }

    #pragma unroll
    for (int j = 0; j < Nn; ++j) sfin[(h * Nn + lane) * Nn + j] = S[j];
}

// ---------------------------------------------------------------- launch
extern "C" void kernel_launch(void* const* d_in, const int* in_sizes, int n_in,
                              void* d_out, int out_size, void* d_ws, size_t ws_size,
                              hipStream_t stream)
{
    const float* r  = (const float*)d_in[0];
    const float* w  = (const float*)d_in[1];
    const float* k  = (const float*)d_in[2];
    const float* v  = (const float*)d_in[3];
    const float* a  = (const float*)d_in[4];
    const float* b  = (const float*)d_in[5];
    const float* st = (const float*)d_in[6];

    float* out  = (float*)d_out;
    float* yl   = out;                       // y region (also y_local scratch)
    float* sfin = out + (size_t)Tt * HN;     // S_final region

    const size_t nTHN = (size_t)Tt * HN;       // 8388608 (rho)
    const size_t nCH  = (size_t)Cc * Hh * NN;  // 8388608 (each of Mt, Pt, Sst)
    const size_t need = nTHN + 3 * nCH;        // scratch element count

    if (ws_size >= need * sizeof(float)) {
        float* ws  = (float*)d_ws;
        float* rho = ws;
        float* Mt  = ws + nTHN;
        float* Pt  = Mt + nCH;
        float* Ss  = Pt + nCH;
        hipLaunchKernelGGL((pass1_scan<float>), dim3(Cc * Hh), dim3(128), 0, stream,
                           r, w, k, v, a, b, yl, rho, Mt, Pt);
        hipLaunchKernelGGL((pass2_chain<float>), dim3(Hh * 8), dim3(512), 0, stream,
                           Mt, Pt, st, Ss, sfin);
        hipLaunchKernelGGL((pass3_fix<float>), dim3(Cc * Hh), dim3(256), 0, stream,
                           rho, Ss, out);
    } else if (ws_size >= need * sizeof(__hip_bfloat16)) {
        __hip_bfloat16* ws  = (__hip_bfloat16*)d_ws;
        __hip_bfloat16* rho = ws;
        __hip_bfloat16* Mt  = ws + nTHN;
        __hip_bfloat16* Pt  = Mt + nCH;
        __hip_bfloat16* Ss  = Pt + nCH;
        hipLaunchKernelGGL((pass1_scan<__hip_bfloat16>), dim3(Cc * Hh), dim3(128), 0, stream,
                           r, w, k, v, a, b, yl, rho, Mt, Pt);
        hipLaunchKernelGGL((pass2_chain<__hip_bfloat16>), dim3(Hh * 8), dim3(512), 0, stream,
                           Mt, Pt, st, Ss, sfin);
        hipLaunchKernelGGL((pass3_fix<__hip_bfloat16>), dim3(Cc * Hh), dim3(256), 0, stream,
                           rho, Ss, out);
    } else {
        // no usable scratch: correct-but-slow sequential scan
        hipLaunchKernelGGL(seq_scan, dim3(Hh), dim3(64), 0, stream,
                           r, w, k, v, a, b, st, yl, sfin);
    }
}

// Round 4
// 461.077 us; speedup vs baseline: 1.4304x; 1.4304x over previous
//
#include <hip/hip_runtime.h>
#include <hip/hip_bf16.h>

// RWKV7 WKV chunked scan. T=4096, H=32, N=64. Output fp32 (y then S_final).
//
// Pass 1 (R5): TWO waves per (chunk, head). Fused P/M scan, column-split:
//   wave wv owns state columns [wv*32, wv*32+32) of BOTH SP and SM. Partial
//   sa/y/q exchanged through double-buffered LDS, ONE barrier per step.
//   readlane broadcasts with inline-constant lane index 0..31.
// Pass 2 (R7, resubmit R8 after infra flake): wave = row r, lane = col j, S in
//   registers, k-dot broadcasts S[r][k] via readlane. M is staged per chunk
//   through LDS (R6's direct per-lane-column global loads were 64-line
//   address-divergent per vmem instr — the hidden ~10x tax): coalesced float4
//   global loads -> LDS tile with stride 68 (+4 pad; bank-quad (j+m)%8 uniform
//   -> conflict-free b128) -> 16x ds_read_b128 per lane. Double-buffered, one
//   barrier/chunk; P prefetched one chunk ahead.
// Pass 3 (R7): S_before tile staged once per block through LDS (same pad),
//   Srow read as 16x ds_read_b128; rho rows loaded coalesced and broadcast
//   via readlane; y read-modify-write coalesced.

#define Tt 4096
#define Hh 32
#define Nn 64
#define Ll 64              // chunk length
#define Cc 64              // number of chunks
#define HN (Hh * Nn)       // 2048
#define NN (Nn * Nn)       // 4096

__device__ __forceinline__ float ldf(const float* p) { return *p; }
__device__ __forceinline__ float ldf(const __hip_bfloat16* p) { return __bfloat162float(*p); }
__device__ __forceinline__ void stf(float* p, float v) { *p = v; }
__device__ __forceinline__ void stf(__hip_bfloat16* p, float v) { *p = __float2bfloat16(v); }

__device__ __forceinline__ float rl(float v, int j) {
    return __int_as_float(__builtin_amdgcn_readlane(__float_as_int(v), j));
}

// unpack a uint (2 bf16) into two floats, elem0 = low 16 bits
__device__ __forceinline__ float bflo(unsigned u) { return __uint_as_float(u << 16); }
__device__ __forceinline__ float bfhi(unsigned u) { return __uint_as_float(u & 0xffff0000u); }

// ---------------------------------------------------------------- pass 1
template <typename ST>
__global__ __launch_bounds__(128, 4)
void pass1_scan(const float* __restrict__ rr, const float* __restrict__ ww,
                const float* __restrict__ kk, const float* __restrict__ vv,
                const float* __restrict__ aa, const float* __restrict__ bb,
                float* __restrict__ ylocal,
                ST* __restrict__ rho, ST* __restrict__ Mt, ST* __restrict__ Pt)
{
    const int c    = blockIdx.x >> 5;      // chunk
    const int h    = blockIdx.x & 31;      // head
    const int tid  = threadIdx.x;
    const int lane = tid & 63;             // row i
    const int wv   = tid >> 6;             // column-half 0/1
    const int j0   = __builtin_amdgcn_readfirstlane(wv << 5);

    // partial-exchange buffers, double-buffered over step parity
    __shared__ float2 ex1[2][2][64];       // [par][wave][row] = {saP, saM} partials
    __shared__ float  ex2[2][2][64];       // [par][wave][row] = partial the OTHER wave finalizes

    float SP[32];                          // P scan, local columns
    float SM[32];                          // M scan, local columns
    #pragma unroll
    for (int jj = 0; jj < 32; ++jj) {
        SP[jj] = 0.0f;
        SM[jj] = (j0 + jj == lane) ? 1.0f : 0.0f;
    }

    int base = (c * Ll * Hh + h) * Nn;     // element offset of step t
    const int lv = j0 + (lane & 31);       // broadcast-source element this lane carries
    float ca = aa[base + lv];
    float cw = ww[base + lv];
    float cb = bb[base + lv];
    float cr = rr[base + lv];
    float ck = kk[base + lv];
    float cv = vv[base + lane];            // per-row value (full vector per lane)

    float py = 0.f, pq = 0.f;              // y/q partials of step t-1 (exchanged next iter)

    for (int t = 0; t < Ll; ++t) {
        // partial sa over local columns (shared a broadcasts between both scans)
        float p0 = 0.f, p1 = 0.f, m0 = 0.f, m1 = 0.f;
        #pragma unroll
        for (int jj = 0; jj < 32; jj += 2) {
            const float a0 = rl(ca, jj), a1 = rl(ca, jj + 1);
            p0 += SP[jj + 0] * a0;  m0 += SM[jj + 0] * a0;
            p1 += SP[jj + 1] * a1;  m1 += SM[jj + 1] * a1;
        }
        const float pP = p0 + p1, pM = m0 + m1;

        ex1[t & 1][wv][lane] = make_float2(pP, pM);
        if (t > 0) ex2[(t - 1) & 1][wv][lane] = (wv == 0) ? pq : py;
        __syncthreads();
        const float2 o = ex1[t & 1][wv ^ 1][lane];
        const float saP = pP + o.x;
        const float saM = pM + o.y;
        if (t > 0) {                        // finish + store step t-1 outputs
            const int ob = base - HN + lane;
            if (wv == 0) ylocal[ob] = py + ex2[(t - 1) & 1][1][lane];
            else         stf(&rho[ob], pq + ex2[(t - 1) & 1][0][lane]);
        }

        // prefetch next step's vectors (uniform branch; hides under update loop)
        float na = 0.f, nw = 0.f, nb = 0.f, nr = 0.f, nk = 0.f, nv = 0.f;
        if (t + 1 < Ll) {
            const int b2 = base + HN;
            na = aa[b2 + lv]; nw = ww[b2 + lv]; nb = bb[b2 + lv];
            nr = rr[b2 + lv]; nk = kk[b2 + lv]; nv = vv[b2 + lane];
        }

        // S = S*w + sa*b (+ v*k); accumulate local y/q partials
        float y0 = 0.f, y1 = 0.f, q0 = 0.f, q1 = 0.f;
        #pragma unroll
        for (int jj = 0; jj < 32; jj += 2) {
            const float w0 = rl(cw, jj), w1 = rl(cw, jj + 1);
            const float b0 = rl(cb, jj), b1 = rl(cb, jj + 1);
            const float k0 = rl(ck, jj), k1 = rl(ck, jj + 1);
            const float r0 = rl(cr, jj), r1 = rl(cr, jj + 1);
            SP[jj + 0] = SP[jj + 0] * w0 + saP * b0 + cv * k0;
            SP[jj + 1] = SP[jj + 1] * w1 + saP * b1 + cv * k1;
            SM[jj + 0] = SM[jj + 0] * w0 + saM * b0;
            SM[jj + 1] = SM[jj + 1] * w1 + saM * b1;
            y0 += SP[jj + 0] * r0;
            y1 += SP[jj + 1] * r1;
            q0 += SM[jj + 0] * r0;
            q1 += SM[jj + 1] * r1;
        }
        py = y0 + y1;
        pq = q0 + q1;

        base += HN;
        ca = na; cw = nw; cb = nb; cr = nr; ck = nk; cv = nv;
    }

    // drain the deferred outputs of the final step
    {
        ex2[(Ll - 1) & 1][wv][lane] = (wv == 0) ? pq : py;
        __syncthreads();
        const int ob = base - HN + lane;
        if (wv == 0) ylocal[ob] = py + ex2[(Ll - 1) & 1][1][lane];
        else         stf(&rho[ob], pq + ex2[(Ll - 1) & 1][0][lane]);
    }

    // chunk-final matrices, stored transposed: [c][h][col j][row lane]
    const size_t mb = ((size_t)(c * Hh) + h) * NN;
    #pragma unroll
    for (int jj = 0; jj < 32; ++jj) {
        stf(&Pt[mb + (size_t)(j0 + jj) * Nn + lane], SP[jj]);
        stf(&Mt[mb + (size_t)(j0 + jj) * Nn + lane], SM[jj]);
    }
}

// ---------------------------------------------------------------- pass 2
#define LMS 68   // LDS row stride (dwords): 64 + 4 pad -> conflict-free b128

template <typename ST>
__global__ __launch_bounds__(512, 2)
void pass2_chain(const ST* __restrict__ Mt, const ST* __restrict__ Pt,
                 const float* __restrict__ st0, ST* __restrict__ Sst,
                 float* __restrict__ sfin)
{
    // bid = g*32 + h  ->  bid%8 = h%8: all 8 row-groups of head h on ONE XCD
    const int bid = blockIdx.x;
    const int h   = bid & 31;
    const int g   = bid >> 5;
    const int tid = threadIdx.x;
    const int j   = tid & 63;          // column (lane)
    const int wv  = tid >> 6;          // wave 0..7
    const int r   = g * 8 + wv;        // row

    __shared__ float lm[2][Nn][LMS];   // [buf][col j][k] = M[k][j] (Mt row j)

    float s = st0[(h * Nn + r) * Nn + j];

    // ---- stage chunk 0 into lm[0] (coalesced global, LDS tile)
    {
        const size_t mb = (size_t)h * NN;
        if constexpr (sizeof(ST) == 2) {
            const uint4 u = *(const uint4*)&Mt[mb + (size_t)tid * 8];
            const int jj = tid >> 3, kc = (tid & 7) * 8;
            float4 f0, f1;
            f0.x = bflo(u.x); f0.y = bfhi(u.x); f0.z = bflo(u.y); f0.w = bfhi(u.y);
            f1.x = bflo(u.z); f1.y = bfhi(u.z); f1.z = bflo(u.w); f1.w = bfhi(u.w);
            *(float4*)&lm[0][jj][kc]     = f0;
            *(float4*)&lm[0][jj][kc + 4] = f1;
        } else {
            const float4 q0 = *(const float4*)&Mt[mb + (size_t)tid * 4];
            const float4 q1 = *(const float4*)&Mt[mb + 2048 + (size_t)tid * 4];
            const int jj = tid >> 4, kc = (tid * 4) & 63;
            *(float4*)&lm[0][jj][kc]      = q0;
            *(float4*)&lm[0][32 + jj][kc] = q1;
        }
    }
    float pp = ldf(&Pt[(size_t)h * NN + (size_t)j * Nn + r]);   // P[r][j] chunk 0
    __syncthreads();

    for (int c = 0; c < Cc; ++c) {
        const int buf = c & 1;
        // S_before[c] out (row-major [r][j], coalesced)
        stf(&Sst[((size_t)(c * Hh) + h) * NN + (size_t)r * Nn + j], s);

        // issue next chunk's stage loads early (latency hides under k-dot)
        const bool pf = (c + 1 < Cc);
        const size_t nb = ((size_t)((c + 1) * Hh) + h) * NN;
        uint4 u = {0, 0, 0, 0};
        float4 q0 = {0, 0, 0, 0}, q1 = {0, 0, 0, 0};
        float ppn = 0.f;
        if (pf) {
            if constexpr (sizeof(ST) == 2) {
                u = *(const uint4*)&Mt[nb + (size_t)tid * 8];
            } else {
                q0 = *(const float4*)&Mt[nb + (size_t)tid * 4];
                q1 = *(const float4*)&Mt[nb + 2048 + (size_t)tid * 4];
            }
            ppn = ldf(&Pt[nb + (size_t)j * Nn + r]);
        }

        // newS[r][j] = sum_k S[r][k] * M[k][j] + P[r][j]
        float a0 = pp, a1 = 0.f, a2 = 0.f, a3 = 0.f;
        #pragma unroll
        for (int m = 0; m < 16; ++m) {
            const float4 mv = *(const float4*)&lm[buf][j][4 * m];
            a0 += rl(s, 4 * m + 0) * mv.x;
            a1 += rl(s, 4 * m + 1) * mv.y;
            a2 += rl(s, 4 * m + 2) * mv.z;
            a3 += rl(s, 4 * m + 3) * mv.w;
        }

        // write next chunk's tile into the other buffer
        if (pf) {
            if constexpr (sizeof(ST) == 2) {
                const int jj = tid >> 3, kc = (tid & 7) * 8;
                float4 f0, f1;
                f0.x = bflo(u.x); f0.y = bfhi(u.x); f0.z = bflo(u.y); f0.w = bfhi(u.y);
                f1.x = bflo(u.z); f1.y = bfhi(u.z); f1.z = bflo(u.w); f1.w = bfhi(u.w);
                *(float4*)&lm[buf ^ 1][jj][kc]     = f0;
                *(float4*)&lm[buf ^ 1][jj][kc + 4] = f1;
            } else {
                const int jj = tid >> 4, kc = (tid * 4) & 63;
                *(float4*)&lm[buf ^ 1][jj][kc]      = q0;
                *(float4*)&lm[buf ^ 1][32 + jj][kc] = q1;
            }
        }

        s = (a0 + a1) + (a2 + a3);
        pp = ppn;
        __syncthreads();
    }

    // final state -> d_out tail (fp32)
    sfin[(h * Nn + r) * Nn + j] = s;
}

// ---------------------------------------------------------------- pass 3
template <typename ST>
__global__ __launch_bounds__(256, 4)
void pass3_fix(const ST* __restrict__ rho, const ST* __restrict__ Sst,
               float* __restrict__ y)
{
    const int c    = blockIdx.x >> 5;   // chunk
    const int h    = blockIdx.x & 31;   // head
    const int tid  = threadIdx.x;
    const int lane = tid & 63;          // output row i
    const int tq   = tid >> 6;          // wave 0..3, handles t = tq*16 + m

    __shared__ float ls[Nn][LMS];       // [row i][col k] = S_before[c][h]

    // stage S tile (row-major in Sst) coalesced -> LDS
    const size_t sb = ((size_t)(c * Hh) + h) * NN;
    if constexpr (sizeof(ST) == 2) {
        #pragma unroll
        for (int half = 0; half < 2; ++half) {
            const int e = half * 2048 + tid * 8;
            const uint4 u = *(const uint4*)&Sst[sb + e];
            const int jj = e >> 6, kc = e & 63;
            float4 f0, f1;
            f0.x = bflo(u.x); f0.y = bfhi(u.x); f0.z = bflo(u.y); f0.w = bfhi(u.y);
            f1.x = bflo(u.z); f1.y = bfhi(u.z); f1.z = bflo(u.w); f1.w = bfhi(u.w);
            *(float4*)&ls[jj][kc]     = f0;
            *(float4*)&ls[jj][kc + 4] = f1;
        }
    } else {
        #pragma unroll
        for (int qq = 0; qq < 4; ++qq) {
            const int e = qq * 1024 + tid * 4;
            const float4 v = *(const float4*)&Sst[sb + e];
            *(float4*)&ls[e >> 6][e & 63] = v;
        }
    }

    // each wave's 16 rho rows, lane-distributed: rt[m] = rho[t][h][lane]
    float rt[16];
    #pragma unroll
    for (int m = 0; m < 16; ++m)
        rt[m] = ldf(&rho[((size_t)(c * Ll + tq * 16 + m) * Hh + h) * Nn + lane]);

    __syncthreads();

    float Srow[Nn];  // S_before[c][h] row `lane` (conflict-free b128 from LDS)
    #pragma unroll
    for (int m = 0; m < 16; ++m) {
        const float4 v = *(const float4*)&ls[lane][4 * m];
        Srow[4*m+0] = v.x; Srow[4*m+1] = v.y; Srow[4*m+2] = v.z; Srow[4*m+3] = v.w;
    }

    #pragma unroll
    for (int m = 0; m < 16; ++m) {
        float a0 = 0.f, a1 = 0.f, a2 = 0.f, a3 = 0.f;
        #pragma unroll
        for (int j = 0; j < Nn; j += 4) {
            a0 += rl(rt[m], j + 0) * Srow[j + 0];
            a1 += rl(rt[m], j + 1) * Srow[j + 1];
            a2 += rl(rt[m], j + 2) * Srow[j + 2];
            a3 += rl(rt[m], j + 3) * Srow[j + 3];
        }
        const size_t oy = ((size_t)(c * Ll + tq * 16 + m) * Hh + h) * Nn + lane;
        y[oy] = y[oy] + ((a0 + a1) + (a2 + a3));
    }
}

// ------------------------------------------- zero-scratch sequential fallback
__global__ __launch_bounds__(64, 1)
void seq_scan(const float* __restrict__ rr, const float* __restrict__ ww,
              const float* __restrict__ kk, const float* __restrict__ vv,
              const float* __restrict__ aa, const float* __restrict__ bb,
              const float* __restrict__ st0,
              float* __restrict__ y, float* __restrict__ sfin)
{
    const int h    = blockIdx.x;
    const int lane = threadIdx.x;          // row i

    float S[Nn];
    #pragma unroll
    for (int j = 0; j < Nn; ++j) S[j] = st0[(h * Nn + lane) * Nn + j];

    int base = h * Nn;
    float ca = aa[base + lane], cw = ww[base + lane], cb = bb[base + lane];
    float cr = rr[base + lane], ck = kk[base + lane], cv = vv[base + lane];

    for (int t = 0; t < Tt; ++t) {
        float na = 0.f, nw = 0.f, nb = 0.f, nr = 0.f, nk = 0.f, nv = 0.f;
        if (t + 1 < Tt) {
            const int b2 = base + HN + lane;
            na = aa[b2]; nw = ww[b2]; nb = bb[b2];
            nr = rr[b2]; nk = kk[b2]; nv = vv[b2];
        }

        float s0 = 0.f, s1 = 0.f;
        #pragma unroll
        for (int j = 0; j < Nn; j += 2) {
            s0 += S[j + 0] * rl(ca, j);
            s1 += S[j + 1] * rl(ca, j + 1);
        }
        const float sa = s0 + s1;

        float y0 = 0.f, y1 = 0.f;
        #pragma unroll
        for (int j = 0; j < Nn; j += 2) {
            const float w0 = rl(cw, j), w1 = rl(cw, j + 1);
            const float b0 = rl(cb, j), b1 = rl(cb, j + 1);
            const float k0 = rl(ck, j), k1 = rl(ck, j + 1);
            const float r0 = rl(cr, j), r1 = rl(cr, j + 1);
            S[j + 0] = S[j + 0] * w0 + sa * b0 + cv * k0;
            S[j + 1] = S[j + 1] * w1 + sa * b1 + cv * k1;
            y0 += S[j + 0] * r0;
            y1 += S[j + 1] * r1;
        }
        y[base + lane] = y0 + y1;
        base += HN;
        ca = na; cw = nw; cb = nb; cr = nr; ck = nk; cv = nv;
    }

    #pragma unroll
    for (int j = 0; j < Nn; ++j) sfin[(h * Nn + lane) * Nn + j] = S[j];
}

// ---------------------------------------------------------------- launch
extern "C" void kernel_launch(void* const* d_in, const int* in_sizes, int n_in,
                              void* d_out, int out_size, void* d_ws, size_t ws_size,
                              hipStream_t stream)
{
    const float* r  = (const float*)d_in[0];
    const float* w  = (const float*)d_in[1];
    const float* k  = (const float*)d_in[2];
    const float* v  = (const float*)d_in[3];
    const float* a  = (const float*)d_in[4];
    const float* b  = (const float*)d_in[5];
    const float* st = (const float*)d_in[6];

    float* out  = (float*)d_out;
    float* yl   = out;                       // y region (also y_local scratch)
    float* sfin = out + (size_t)Tt * HN;     // S_final region

    const size_t nTHN = (size_t)Tt * HN;       // 8388608 (rho)
    const size_t nCH  = (size_t)Cc * Hh * NN;  // 8388608 (each of Mt, Pt, Sst)
    const size_t need = nTHN + 3 * nCH;        // scratch element count

    if (ws_size >= need * sizeof(float)) {
        float* ws  = (float*)d_ws;
        float* rho = ws;
        float* Mt  = ws + nTHN;
        float* Pt  = Mt + nCH;
        float* Ss  = Pt + nCH;
        hipLaunchKernelGGL((pass1_scan<float>), dim3(Cc * Hh), dim3(128), 0, stream,
                           r, w, k, v, a, b, yl, rho, Mt, Pt);
        hipLaunchKernelGGL((pass2_chain<float>), dim3(Hh * 8), dim3(512), 0, stream,
                           Mt, Pt, st, Ss, sfin);
        hipLaunchKernelGGL((pass3_fix<float>), dim3(Cc * Hh), dim3(256), 0, stream,
                           rho, Ss, out);
    } else if (ws_size >= need * sizeof(__hip_bfloat16)) {
        __hip_bfloat16* ws  = (__hip_bfloat16*)d_ws;
        __hip_bfloat16* rho = ws;
        __hip_bfloat16* Mt  = ws + nTHN;
        __hip_bfloat16* Pt  = Mt + nCH;
        __hip_bfloat16* Ss  = Pt + nCH;
        hipLaunchKernelGGL((pass1_scan<__hip_bfloat16>), dim3(Cc * Hh), dim3(128), 0, stream,
                           r, w, k, v, a, b, yl, rho, Mt, Pt);
        hipLaunchKernelGGL((pass2_chain<__hip_bfloat16>), dim3(Hh * 8), dim3(512), 0, stream,
                           Mt, Pt, st, Ss, sfin);
        hipLaunchKernelGGL((pass3_fix<__hip_bfloat16>), dim3(Cc * Hh), dim3(256), 0, stream,
                           rho, Ss, out);
    } else {
        // no usable scratch: correct-but-slow sequential scan
        hipLaunchKernelGGL(seq_scan, dim3(Hh), dim3(64), 0, stream,
                           r, w, k, v, a, b, st, yl, sfin);
    }
}